// Round 3
// baseline (1730.112 us; speedup 1.0000x reference)
//
#include <hip/hip_runtime.h>
#include <math.h>

#define BB 64
#define NN 256
#define DD 768
#define GG 300
#define KK 10
#define NEGV -9e15f

// block reduction helpers (blockDim multiple of 64, <=256). s must have >=4 floats.
__device__ __forceinline__ float blkReduceSum(float v, float* s){
  for(int o=32;o>0;o>>=1) v += __shfl_down(v,o,64);
  int nw = blockDim.x>>6;
  __syncthreads();
  if((threadIdx.x&63)==0) s[threadIdx.x>>6]=v;
  __syncthreads();
  float r=s[0];
  for(int i=1;i<nw;i++) r+=s[i];
  return r;
}
__device__ __forceinline__ float blkReduceMax(float v, float* s){
  for(int o=32;o>0;o>>=1) v = fmaxf(v, __shfl_down(v,o,64));
  int nw = blockDim.x>>6;
  __syncthreads();
  if((threadIdx.x&63)==0) s[threadIdx.x>>6]=v;
  __syncthreads();
  float r=s[0];
  for(int i=1;i<nw;i++) r=fmaxf(r,s[i]);
  return r;
}

// ---------------------------------------------------------------------------
// Semantic channel prep: one block per batch, 256 threads.
// Emits v[b,:] (top-K cosine sims scattered to their node slots, 0 elsewhere)
// and S[b] = sum of top-K values. The semantic adjacency is the closed form
//   adj[i,j] = ((v_i+v_j)/2 + (i==j)) / ((N*v_i + S)/2 + 1 + 1e-8)
// and is only ever consumed as a >0 mask, so we never materialize it.
// ---------------------------------------------------------------------------
__global__ __launch_bounds__(256) void k_semprep(const float* __restrict__ h,
                                                 const float* __restrict__ amask,
                                                 float* __restrict__ vout,
                                                 float* __restrict__ Sout){
  int b = blockIdx.x, tid = threadIdx.x;
  __shared__ float s_mask[NN];
  __shared__ float s_arep[DD];
  __shared__ float s_sim[NN];
  __shared__ float s_red[4];
  __shared__ float s_v[NN];
  __shared__ float s_bv[4]; __shared__ int s_bi[4];
  __shared__ float s_tv[KK]; __shared__ int s_ti[KK];

  s_mask[tid] = amask[b*NN+tid];
  __syncthreads();
  float cnt = blkReduceSum(s_mask[tid], s_red);

  // a_repr (masked mean over nodes)
  for(int d=tid; d<DD; d+=256){
    float a=0.f;
    for(int n=0;n<NN;n++) a += h[((size_t)b*NN+n)*DD+d] * s_mask[n];
    s_arep[d] = a/(cnt+1e-8f);
  }
  __syncthreads();
  float pa=0.f;
  for(int d=tid; d<DD; d+=256) pa += s_arep[d]*s_arep[d];
  float na = blkReduceSum(pa, s_red);
  float nac = fmaxf(sqrtf(na), 1e-12f);

  // cosine sim per node (thread tid = node tid)
  {
    const float* hr = h + ((size_t)b*NN+tid)*DD;
    float dot=0.f, nn=0.f;
    for(int d=0; d<DD; d++){ float x=hr[d]; dot += x*s_arep[d]; nn += x*x; }
    nn = fmaxf(sqrtf(nn), 1e-12f);
    s_sim[tid] = dot/(nn*nac);
  }
  __syncthreads();

  // top-K via K rounds of block argmax (lowest-index tie-break = stable top_k)
  float v = s_sim[tid];
  int lane = tid&63, w = tid>>6;
  for(int k=0;k<KK;k++){
    float bv = v; int bi_ = tid;
    for(int o=32;o>0;o>>=1){
      float ov = __shfl_down(bv,o,64); int oi = __shfl_down(bi_,o,64);
      if(ov>bv || (ov==bv && oi<bi_)){ bv=ov; bi_=oi; }
    }
    if(lane==0){ s_bv[w]=bv; s_bi[w]=bi_; }
    __syncthreads();
    float gb = s_bv[0]; int gi = s_bi[0];
    for(int i=1;i<4;i++){ if(s_bv[i]>gb || (s_bv[i]==gb && s_bi[i]<gi)){ gb=s_bv[i]; gi=s_bi[i]; } }
    if(tid==0){ s_tv[k]=gb; s_ti[k]=gi; }
    if(tid==gi) v = -1e30f;
    __syncthreads();
  }
  s_v[tid]=0.f;
  __syncthreads();
  if(tid<KK) s_v[s_ti[tid]] = s_tv[tid];
  __syncthreads();
  float S=0.f;
  for(int k=0;k<KK;k++) S += s_tv[k];

  vout[b*NN+tid] = s_v[tid];
  if(tid==0) Sout[b] = S;
}

// ---------------------------------------------------------------------------
// Linear: Y1 = X@W1 + posemb[positions];  (opt) Y2 = X@W2 + tb
// 8 rows per block, 256 threads; thread owns cols {tid, tid+256 (if <300)}
// ---------------------------------------------------------------------------
template<int KDIM, bool HASW2>
__global__ __launch_bounds__(256) void k_linear(const float* __restrict__ X,
    const float* __restrict__ W1, const float* __restrict__ W2,
    const float* __restrict__ posemb, const int* __restrict__ positions,
    const float* __restrict__ tb, float* __restrict__ Y1, float* __restrict__ Y2){
  __shared__ float s_x[8*KDIM];
  int tid = threadIdx.x;
  int row0 = blockIdx.x*8;
  for(int idx=tid; idx<8*KDIM; idx+=256){
    int r = idx / KDIM, k = idx % KDIM;
    s_x[idx] = X[(size_t)(row0+r)*KDIM + k];
  }
  __syncthreads();
  bool has2 = tid < (GG-256);   // 44
  float a1[8]={0,0,0,0,0,0,0,0}, b1[8]={0,0,0,0,0,0,0,0};
  float a2[8]={0,0,0,0,0,0,0,0}, b2[8]={0,0,0,0,0,0,0,0};
  for(int k=0;k<KDIM;k++){
    float w1a = W1[(size_t)k*GG+tid];
    float w1b = has2 ? W1[(size_t)k*GG+tid+256] : 0.f;
    float w2a=0.f, w2b=0.f;
    if(HASW2){ w2a = W2[(size_t)k*GG+tid]; w2b = has2 ? W2[(size_t)k*GG+tid+256] : 0.f; }
    #pragma unroll
    for(int r=0;r<8;r++){
      float x = s_x[r*KDIM+k];
      a1[r] = fmaf(x,w1a,a1[r]); b1[r] = fmaf(x,w1b,b1[r]);
      if(HASW2){ a2[r] = fmaf(x,w2a,a2[r]); b2[r] = fmaf(x,w2b,b2[r]); }
    }
  }
  for(int r=0;r<8;r++){
    int row = row0+r;
    int p = positions[row];
    size_t o = (size_t)row*GG;
    Y1[o+tid] = a1[r] + posemb[(size_t)p*GG+tid];
    if(has2) Y1[o+tid+256] = b1[r] + posemb[(size_t)p*GG+tid+256];
    if(HASW2){
      Y2[o+tid] = a2[r] + tb[tid];
      if(has2) Y2[o+tid+256] = b2[r] + tb[tid+256];
    }
  }
}

// ---------------------------------------------------------------------------
// f1/f2: one wave per row
// ---------------------------------------------------------------------------
__global__ __launch_bounds__(256) void k_f1f2(const float* __restrict__ Wh,
    const float* __restrict__ a1, const float* __restrict__ a2,
    float* __restrict__ f1, float* __restrict__ f2){
  int row = blockIdx.x*4 + (threadIdx.x>>6);
  int lane = threadIdx.x&63;
  const float* wr = Wh + (size_t)row*GG;
  float s1=0.f, s2=0.f;
  for(int c=lane;c<GG;c+=64){ float wv=wr[c]; s1 += wv*a1[c]; s2 += wv*a2[c]; }
  for(int o=32;o>0;o>>=1){ s1+=__shfl_down(s1,o,64); s2+=__shfl_down(s2,o,64); }
  if(lane==0){ f1[row]=s1; f2[row]=s2; }
}

// ---------------------------------------------------------------------------
// Attention: masked-leakyrelu softmax over j, then hp = attn @ Wh
// 8 rows (i) per block, 256 threads (thread j for softmax; thread c for agg)
// SEM: mask from closed-form semantic adjacency sign; else synadj>0.
// ---------------------------------------------------------------------------
template<bool SEM>
__global__ __launch_bounds__(256) void k_attn(const float* __restrict__ Wh,
    const float* __restrict__ f1, const float* __restrict__ f2,
    const int* __restrict__ adjI, const float* __restrict__ vvec,
    const float* __restrict__ Svec, float* __restrict__ hp){
  int b = blockIdx.x, i0 = blockIdx.y*8, tid = threadIdx.x;
  __shared__ float s_f2[NN];
  __shared__ float s_v[NN];
  __shared__ float s_p[8][NN];
  __shared__ float s_red[4];
  s_f2[tid] = f2[b*NN+tid];
  float S = 0.f;
  if(SEM){ s_v[tid] = vvec[b*NN+tid]; S = Svec[b]; }
  __syncthreads();
  for(int r=0;r<8;r++){
    int i = i0+r;
    float e = f1[b*NN+i] + s_f2[tid];
    e = e>0.f ? e : 0.2f*e;
    bool m;
    if(SEM){
      float vi = s_v[i];
      float denom = 0.5f*((float)NN*vi + S) + 1.f + 1e-8f;
      float val = 0.5f*(vi + s_v[tid]) + (i==tid ? 1.f : 0.f);
      m = (denom > 0.f) ? (val > 0.f) : (val < 0.f);
    } else {
      m = adjI[((size_t)b*NN+i)*NN+tid] > 0;
    }
    e = m ? e : NEGV;
    float mx = blkReduceMax(e, s_red);
    float p = expf(e - mx);
    float sm = blkReduceSum(p, s_red);
    s_p[r][tid] = p/sm;
  }
  __syncthreads();
  bool has2 = tid < (GG-256);
  float aa[8]={0,0,0,0,0,0,0,0}, ab[8]={0,0,0,0,0,0,0,0};
  const float* whb = Wh + (size_t)b*NN*GG;
  for(int j=0;j<NN;j++){
    float wa = whb[(size_t)j*GG+tid];
    float wb = has2 ? whb[(size_t)j*GG+tid+256] : 0.f;
    #pragma unroll
    for(int r=0;r<8;r++){ float p=s_p[r][j]; aa[r]=fmaf(p,wa,aa[r]); ab[r]=fmaf(p,wb,ab[r]); }
  }
  for(int r=0;r<8;r++){
    size_t o = ((size_t)b*NN + i0+r)*GG;
    hp[o+tid] = aa[r];
    if(has2) hp[o+tid+256] = ab[r];
  }
}

// ---------------------------------------------------------------------------
// LayerNorm(hp+res)*g+b then ReLU. One block (128 thr) per row.
// Safe for out == res (each element read before written, rows disjoint).
// ---------------------------------------------------------------------------
__global__ __launch_bounds__(128) void k_lnrelu(const float* __restrict__ hp,
    const float* __restrict__ res, const float* __restrict__ g,
    const float* __restrict__ bt, float* __restrict__ out){
  __shared__ float s_red[4];
  int row = blockIdx.x, tid = threadIdx.x;
  size_t o = (size_t)row*GG;
  bool h3 = tid < (GG-256);  // 44
  float x0 = hp[o+tid]     + res[o+tid];
  float x1 = hp[o+tid+128] + res[o+tid+128];
  float x2 = h3 ? hp[o+tid+256] + res[o+tid+256] : 0.f;
  float sum = blkReduceSum(x0+x1+x2, s_red);
  float m = sum/(float)GG;
  float d0=x0-m, d1=x1-m, d2=h3?(x2-m):0.f;
  float vs = blkReduceSum(d0*d0+d1*d1+d2*d2, s_red);
  float inv = 1.0f/sqrtf(vs/(float)GG + 1e-5f);
  float wv;
  wv = d0*inv*g[tid]     + bt[tid];     out[o+tid]     = fmaxf(wv,0.f);
  wv = d1*inv*g[tid+128] + bt[tid+128]; out[o+tid+128] = fmaxf(wv,0.f);
  if(h3){ wv = d2*inv*g[tid+256] + bt[tid+256]; out[o+tid+256] = fmaxf(wv,0.f); }
}

// ---------------------------------------------------------------------------
// Fusion: out = relu(concat(hs,hm) @ W + b)
// concat(hs,hm)@W == hs@W[0:300] + hm@W[300:600] — two-stage LDS (9.6 KB)
// ---------------------------------------------------------------------------
__global__ __launch_bounds__(256) void k_fusion(const float* __restrict__ hs,
    const float* __restrict__ hm, const float* __restrict__ W,
    const float* __restrict__ bias, float* __restrict__ out){
  __shared__ float s_x[8*GG];
  int tid = threadIdx.x, row0 = blockIdx.x*8;
  bool has2 = tid < (GG-256);
  float a[8]={0,0,0,0,0,0,0,0}, bacc[8]={0,0,0,0,0,0,0,0};
  for(int stg=0; stg<2; stg++){
    const float* src = stg ? hm : hs;
    __syncthreads();
    for(int idx=tid; idx<8*GG; idx+=256){
      int r = idx/GG, k = idx%GG;
      s_x[idx] = src[(size_t)(row0+r)*GG + k];
    }
    __syncthreads();
    for(int k=0;k<GG;k++){
      int kk = stg*GG + k;
      float wa = W[(size_t)kk*GG+tid];
      float wb = has2 ? W[(size_t)kk*GG+tid+256] : 0.f;
      #pragma unroll
      for(int r=0;r<8;r++){ float x=s_x[r*GG+k]; a[r]=fmaf(x,wa,a[r]); bacc[r]=fmaf(x,wb,bacc[r]); }
    }
  }
  for(int r=0;r<8;r++){
    size_t o = (size_t)(row0+r)*GG;
    float y = a[r] + bias[tid];
    out[o+tid] = fmaxf(y,0.f);
    if(has2){ y = bacc[r] + bias[tid+256]; out[o+tid+256] = fmaxf(y,0.f); }
  }
}

// ---------------------------------------------------------------------------
extern "C" void kernel_launch(void* const* d_in, const int* in_sizes, int n_in,
                              void* d_out, int out_size, void* d_ws, size_t ws_size,
                              hipStream_t stream){
  const float* h     = (const float*)d_in[0];
  const float* amask = (const float*)d_in[1];
  const float *syn0_W=(const float*)d_in[2], *syn0_a1=(const float*)d_in[3], *syn0_a2=(const float*)d_in[4],
              *syn0_pos=(const float*)d_in[5], *syn0_tW=(const float*)d_in[6], *syn0_tb=(const float*)d_in[7],
              *syn0_g=(const float*)d_in[8], *syn0_b=(const float*)d_in[9];
  const float *syn1_W=(const float*)d_in[10], *syn1_a1=(const float*)d_in[11], *syn1_a2=(const float*)d_in[12],
              *syn1_pos=(const float*)d_in[13], *syn1_g=(const float*)d_in[14], *syn1_b=(const float*)d_in[15];
  const float *sem0_W=(const float*)d_in[16], *sem0_a1=(const float*)d_in[17], *sem0_a2=(const float*)d_in[18],
              *sem0_pos=(const float*)d_in[19], *sem0_tW=(const float*)d_in[20], *sem0_tb=(const float*)d_in[21],
              *sem0_g=(const float*)d_in[22], *sem0_b=(const float*)d_in[23];
  const float *sem1_W=(const float*)d_in[24], *sem1_a1=(const float*)d_in[25], *sem1_a2=(const float*)d_in[26],
              *sem1_pos=(const float*)d_in[27], *sem1_g=(const float*)d_in[28], *sem1_b=(const float*)d_in[29];
  const float *fus_W=(const float*)d_in[30], *fus_b=(const float*)d_in[31];
  const int* synadj    = (const int*)d_in[32];
  const int* positions = (const int*)d_in[33];
  float* out = (float*)d_out;

  float* ws   = (float*)d_ws;
  float* vvec = ws;                 // 16384
  float* Svec = vvec + 16384;       // 64
  float* f1   = Svec + 64;          // 16384
  float* f2   = f1 + 16384;         // 16384
  float* Wh   = f2 + 16384;         // 4,915,200 each below
  float* T1   = Wh + 4915200;
  float* T2   = T1 + 4915200;
  float* T3   = T2 + 4915200;       // total ~78.9 MB

  dim3 gAttn(BB, NN/8);
  int gLin = BB*NN/8;      // 2048
  int gF   = BB*NN/4;      // 4096
  int gLN  = BB*NN;        // 16384

  k_semprep<<<BB,256,0,stream>>>(h, amask, vvec, Svec);

  // syntactic channel, layer 0:  T3 = relu(LN(attn + h@tW+tb))
  k_linear<DD,true><<<gLin,256,0,stream>>>(h, syn0_W, syn0_tW, syn0_pos, positions, syn0_tb, Wh, T1);
  k_f1f2<<<gF,256,0,stream>>>(Wh, syn0_a1, syn0_a2, f1, f2);
  k_attn<false><<<gAttn,256,0,stream>>>(Wh, f1, f2, synadj, nullptr, nullptr, T2);
  k_lnrelu<<<gLN,128,0,stream>>>(T2, T1, syn0_g, syn0_b, T3);
  // syntactic channel, layer 1 (identity residual): T3 = relu(LN(attn + T3))
  k_linear<GG,false><<<gLin,256,0,stream>>>(T3, syn1_W, nullptr, syn1_pos, positions, nullptr, Wh, nullptr);
  k_f1f2<<<gF,256,0,stream>>>(Wh, syn1_a1, syn1_a2, f1, f2);
  k_attn<false><<<gAttn,256,0,stream>>>(Wh, f1, f2, synadj, nullptr, nullptr, T2);
  k_lnrelu<<<gLN,128,0,stream>>>(T2, T3, syn1_g, syn1_b, T3);

  // semantic channel, layer 0: T1 = relu(LN(attn + h@tW+tb))
  k_linear<DD,true><<<gLin,256,0,stream>>>(h, sem0_W, sem0_tW, sem0_pos, positions, sem0_tb, Wh, T1);
  k_f1f2<<<gF,256,0,stream>>>(Wh, sem0_a1, sem0_a2, f1, f2);
  k_attn<true><<<gAttn,256,0,stream>>>(Wh, f1, f2, nullptr, vvec, Svec, T2);
  k_lnrelu<<<gLN,128,0,stream>>>(T2, T1, sem0_g, sem0_b, T1);
  // semantic channel, layer 1: T1 = relu(LN(attn + T1))
  k_linear<GG,false><<<gLin,256,0,stream>>>(T1, sem1_W, nullptr, sem1_pos, positions, nullptr, Wh, nullptr);
  k_f1f2<<<gF,256,0,stream>>>(Wh, sem1_a1, sem1_a2, f1, f2);
  k_attn<true><<<gAttn,256,0,stream>>>(Wh, f1, f2, nullptr, vvec, Svec, T2);
  k_lnrelu<<<gLN,128,0,stream>>>(T2, T1, sem1_g, sem1_b, T1);

  // fusion
  k_fusion<<<gLin,256,0,stream>>>(T3, T1, fus_W, fus_b, out);
}

// Round 4
// 1021.998 us; speedup vs baseline: 1.6929x; 1.6929x over previous
//
#include <hip/hip_runtime.h>
#include <hip/hip_bf16.h>
#include <math.h>

#define BB 64
#define NN 256
#define DD 768
#define GG 300
#define KK 10
#define NEGV -9e15f

typedef __attribute__((ext_vector_type(8)))  short short8;
typedef __attribute__((ext_vector_type(4)))  short short4v;
typedef __attribute__((ext_vector_type(16))) float f32x16;

static __device__ __forceinline__ short f2bf(float f){
  __hip_bfloat16 b = __float2bfloat16(f);
  return __builtin_bit_cast(short, b);
}

// block reduction helpers (blockDim multiple of 64, <=256). s must have >=4 floats.
__device__ __forceinline__ float blkReduceSum(float v, float* s){
  for(int o=32;o>0;o>>=1) v += __shfl_down(v,o,64);
  int nw = blockDim.x>>6;
  __syncthreads();
  if((threadIdx.x&63)==0) s[threadIdx.x>>6]=v;
  __syncthreads();
  float r=s[0];
  for(int i=1;i<nw;i++) r+=s[i];
  return r;
}
__device__ __forceinline__ float blkReduceMax(float v, float* s){
  for(int o=32;o>0;o>>=1) v = fmaxf(v, __shfl_down(v,o,64));
  int nw = blockDim.x>>6;
  __syncthreads();
  if((threadIdx.x&63)==0) s[threadIdx.x>>6]=v;
  __syncthreads();
  float r=s[0];
  for(int i=1;i<nw;i++) r=fmaxf(r,s[i]);
  return r;
}

// ---------------------------------------------------------------------------
// Semantic channel prep (unchanged from round 3): emits scattered top-K vector
// v[b,:] and S[b]; semantic adjacency reconstructed in closed form by k_attn.
// ---------------------------------------------------------------------------
__global__ __launch_bounds__(256) void k_semprep(const float* __restrict__ h,
                                                 const float* __restrict__ amask,
                                                 float* __restrict__ vout,
                                                 float* __restrict__ Sout){
  int b = blockIdx.x, tid = threadIdx.x;
  __shared__ float s_mask[NN];
  __shared__ float s_arep[DD];
  __shared__ float s_sim[NN];
  __shared__ float s_red[4];
  __shared__ float s_v[NN];
  __shared__ float s_bv[4]; __shared__ int s_bi[4];
  __shared__ float s_tv[KK]; __shared__ int s_ti[KK];

  s_mask[tid] = amask[b*NN+tid];
  __syncthreads();
  float cnt = blkReduceSum(s_mask[tid], s_red);

  for(int d=tid; d<DD; d+=256){
    float a=0.f;
    for(int n=0;n<NN;n++) a += h[((size_t)b*NN+n)*DD+d] * s_mask[n];
    s_arep[d] = a/(cnt+1e-8f);
  }
  __syncthreads();
  float pa=0.f;
  for(int d=tid; d<DD; d+=256) pa += s_arep[d]*s_arep[d];
  float na = blkReduceSum(pa, s_red);
  float nac = fmaxf(sqrtf(na), 1e-12f);

  {
    const float* hr = h + ((size_t)b*NN+tid)*DD;
    float dot=0.f, nn=0.f;
    for(int d=0; d<DD; d++){ float x=hr[d]; dot += x*s_arep[d]; nn += x*x; }
    nn = fmaxf(sqrtf(nn), 1e-12f);
    s_sim[tid] = dot/(nn*nac);
  }
  __syncthreads();

  float v = s_sim[tid];
  int lane = tid&63, w = tid>>6;
  for(int k=0;k<KK;k++){
    float bv = v; int bi_ = tid;
    for(int o=32;o>0;o>>=1){
      float ov = __shfl_down(bv,o,64); int oi = __shfl_down(bi_,o,64);
      if(ov>bv || (ov==bv && oi<bi_)){ bv=ov; bi_=oi; }
    }
    if(lane==0){ s_bv[w]=bv; s_bi[w]=bi_; }
    __syncthreads();
    float gb = s_bv[0]; int gi = s_bi[0];
    for(int i=1;i<4;i++){ if(s_bv[i]>gb || (s_bv[i]==gb && s_bi[i]<gi)){ gb=s_bv[i]; gi=s_bi[i]; } }
    if(tid==0){ s_tv[k]=gb; s_ti[k]=gi; }
    if(tid==gi) v = -1e30f;
    __syncthreads();
  }
  s_v[tid]=0.f;
  __syncthreads();
  if(tid<KK) s_v[s_ti[tid]] = s_tv[tid];
  __syncthreads();
  float S=0.f;
  for(int k=0;k<KK;k++) S += s_tv[k];

  vout[b*NN+tid] = s_v[tid];
  if(tid==0) Sout[b] = S;
}

// ---------------------------------------------------------------------------
// Weight cast+transpose+pad: dst[n][k] (bf16, [NPAD][KPAD]) from W[k][300].
// Dual packing: n<300 -> W1, n in [n2off, n2off+300) -> W2, else 0. k>=K -> 0.
// ---------------------------------------------------------------------------
__global__ __launch_bounds__(256) void k_wcast(const float* __restrict__ W1,
    const float* __restrict__ W2, short* __restrict__ dst,
    int K, int KPAD, int NPAD, int n2off){
  int idx = blockIdx.x*256 + threadIdx.x;
  if(idx >= NPAD*KPAD) return;
  int n = idx / KPAD, k = idx % KPAD;
  float v = 0.f;
  if(k < K){
    if(n < 300) v = W1[(size_t)k*300 + n];
    else if(W2 && n >= n2off && n < n2off+300) v = W2[(size_t)k*300 + (n - n2off)];
  }
  dst[idx] = f2bf(v);
}

// ---------------------------------------------------------------------------
// MFMA GEMM: Y = X[M][KPAD] @ Wt^T, Wt[NPAD][KPAD] bf16 (pre-transposed).
// Block: 256 thr = 4 waves (2 rowgrp x 2 colgrp). BM=64, BN=320, BK=32.
// mfma_f32_32x32x16_bf16; verified layouts:
//   A[m=lane&31][k=(lane>>5)*8+j]; B rows of Wt give contiguous k;
//   C/D: col=lane&31, row=(reg&3)+8*(reg>>2)+4*(lane>>5).
// LDS rows padded to 40 shorts (80B): 16B-aligned + bank-uniform for b128.
// MODE 0: Y1 = acc + posemb[positions[row]][n]           (n<300)
// MODE 1: + second half (Bt cols 320..620): Y2 = acc + tvec[n-320]
// MODE 2: Y1 = relu(acc + tvec[n])                        (fusion -> d_out)
// ---------------------------------------------------------------------------
template<int KPAD, int MODE, typename XT>
__global__ __launch_bounds__(256) void k_gemm(const XT* __restrict__ X,
    const short* __restrict__ Bt, const float* __restrict__ posemb,
    const int* __restrict__ positions, const float* __restrict__ tvec,
    float* __restrict__ Y1, float* __restrict__ Y2){
  __shared__ __align__(16) short sX[64*40];
  __shared__ __align__(16) short sB[320*40];
  const int tid = threadIdx.x;
  const int lane = tid & 63, wave = tid >> 6;
  const int rgrp = wave & 1, cgrp = wave >> 1;
  const int row0 = blockIdx.x * 64;
  const int ncol0 = blockIdx.y * 320;
  const int lo = lane & 31, hi = lane >> 5;

  f32x16 acc[5];
  #pragma unroll
  for(int t=0;t<5;t++)
    #pragma unroll
    for(int i=0;i<16;i++) acc[t][i] = 0.f;

  for(int k0=0; k0<KPAD; k0+=32){
    __syncthreads();
    if constexpr (sizeof(XT)==4){   // fp32 X: convert to bf16 during staging
      #pragma unroll
      for(int c=tid; c<512; c+=256){
        int r=c>>3, cc=c&7;
        float4 v = *(const float4*)(X + (size_t)(row0+r)*KPAD + k0 + cc*4);
        short4v s; s.x=f2bf(v.x); s.y=f2bf(v.y); s.z=f2bf(v.z); s.w=f2bf(v.w);
        *(short4v*)(sX + r*40 + cc*4) = s;
      }
    } else {                        // bf16 X
      if(tid < 256){
        int r=tid>>2, cc=tid&3;
        *(short8*)(sX + r*40 + cc*8) = *(const short8*)(X + (size_t)(row0+r)*KPAD + k0 + cc*8);
      }
    }
    #pragma unroll
    for(int c=tid; c<1280; c+=256){
      int r=c>>2, cc=c&3;
      *(short8*)(sB + r*40 + cc*8) = *(const short8*)(Bt + (size_t)(ncol0+r)*KPAD + k0 + cc*8);
    }
    __syncthreads();
    #pragma unroll
    for(int ss=0; ss<2; ss++){
      int kb = ss*16 + hi*8;
      short8 a = *(const short8*)(sX + (rgrp*32 + lo)*40 + kb);
      #pragma unroll
      for(int t=0;t<5;t++){
        short8 b = *(const short8*)(sB + (cgrp*160 + t*32 + lo)*40 + kb);
        acc[t] = __builtin_amdgcn_mfma_f32_32x32x16_bf16(a, b, acc[t], 0, 0, 0);
      }
    }
  }

  #pragma unroll
  for(int r=0;r<16;r++){
    int row = row0 + rgrp*32 + (r&3) + 8*(r>>2) + 4*hi;
    int p = 0;
    if(MODE!=2) p = positions[row];
    #pragma unroll
    for(int t=0;t<5;t++){
      int nc = ncol0 + cgrp*160 + t*32 + lo;
      float v = acc[t][r];
      if(MODE==2){
        if(nc < 300) Y1[(size_t)row*300 + nc] = fmaxf(v + tvec[nc], 0.f);
      } else {
        if(nc < 300) Y1[(size_t)row*300 + nc] = v + posemb[(size_t)p*300 + nc];
        else if(MODE==1 && nc>=320 && nc<620) Y2[(size_t)row*300 + (nc-320)] = v + tvec[nc-320];
      }
    }
  }
}

// ---------------------------------------------------------------------------
// f1/f2: one wave per row (unchanged)
// ---------------------------------------------------------------------------
__global__ __launch_bounds__(256) void k_f1f2(const float* __restrict__ Wh,
    const float* __restrict__ a1, const float* __restrict__ a2,
    float* __restrict__ f1, float* __restrict__ f2){
  int row = blockIdx.x*4 + (threadIdx.x>>6);
  int lane = threadIdx.x&63;
  const float* wr = Wh + (size_t)row*GG;
  float s1=0.f, s2=0.f;
  for(int c=lane;c<GG;c+=64){ float wv=wr[c]; s1 += wv*a1[c]; s2 += wv*a2[c]; }
  for(int o=32;o>0;o>>=1){ s1+=__shfl_down(s1,o,64); s2+=__shfl_down(s2,o,64); }
  if(lane==0){ f1[row]=s1; f2[row]=s2; }
}

// ---------------------------------------------------------------------------
// Attention (unchanged): masked-leakyrelu softmax, then hp = attn @ Wh
// ---------------------------------------------------------------------------
template<bool SEM>
__global__ __launch_bounds__(256) void k_attn(const float* __restrict__ Wh,
    const float* __restrict__ f1, const float* __restrict__ f2,
    const int* __restrict__ adjI, const float* __restrict__ vvec,
    const float* __restrict__ Svec, float* __restrict__ hp){
  int b = blockIdx.x, i0 = blockIdx.y*8, tid = threadIdx.x;
  __shared__ float s_f2[NN];
  __shared__ float s_v[NN];
  __shared__ float s_p[8][NN];
  __shared__ float s_red[4];
  s_f2[tid] = f2[b*NN+tid];
  float S = 0.f;
  if(SEM){ s_v[tid] = vvec[b*NN+tid]; S = Svec[b]; }
  __syncthreads();
  for(int r=0;r<8;r++){
    int i = i0+r;
    float e = f1[b*NN+i] + s_f2[tid];
    e = e>0.f ? e : 0.2f*e;
    bool m;
    if(SEM){
      float vi = s_v[i];
      float denom = 0.5f*((float)NN*vi + S) + 1.f + 1e-8f;
      float val = 0.5f*(vi + s_v[tid]) + (i==tid ? 1.f : 0.f);
      m = (denom > 0.f) ? (val > 0.f) : (val < 0.f);
    } else {
      m = adjI[((size_t)b*NN+i)*NN+tid] > 0;
    }
    e = m ? e : NEGV;
    float mx = blkReduceMax(e, s_red);
    float p = expf(e - mx);
    float sm = blkReduceSum(p, s_red);
    s_p[r][tid] = p/sm;
  }
  __syncthreads();
  bool has2 = tid < (GG-256);
  float aa[8]={0,0,0,0,0,0,0,0}, ab[8]={0,0,0,0,0,0,0,0};
  const float* whb = Wh + (size_t)b*NN*GG;
  for(int j=0;j<NN;j++){
    float wa = whb[(size_t)j*GG+tid];
    float wb = has2 ? whb[(size_t)j*GG+tid+256] : 0.f;
    #pragma unroll
    for(int r=0;r<8;r++){ float p=s_p[r][j]; aa[r]=fmaf(p,wa,aa[r]); ab[r]=fmaf(p,wb,ab[r]); }
  }
  for(int r=0;r<8;r++){
    size_t o = ((size_t)b*NN + i0+r)*GG;
    hp[o+tid] = aa[r];
    if(has2) hp[o+tid+256] = ab[r];
  }
}

// ---------------------------------------------------------------------------
// LayerNorm(hp+res)*g+b then ReLU. One block (128 thr) per row.
// Optional fp32 out (strided, zero-pads cols [300,f32pad)) and bf16 out
// (strided+offset, zero-pads cols [300,bfpad)). Safe for f32out==res.
// ---------------------------------------------------------------------------
__global__ __launch_bounds__(128) void k_lnrelu(const float* __restrict__ hp,
    const float* __restrict__ res, int res_ld,
    const float* __restrict__ g, const float* __restrict__ bt,
    float* __restrict__ f32out, int f32_ld, int f32pad,
    short* __restrict__ bfout, int bf_ld, int bf_off, int bfpad){
  __shared__ float s_red[4];
  int row = blockIdx.x, tid = threadIdx.x;
  size_t oh = (size_t)row*GG;
  size_t orr = (size_t)row*res_ld;
  bool h3 = tid < (GG-256);  // 44
  float x0 = hp[oh+tid]     + res[orr+tid];
  float x1 = hp[oh+tid+128] + res[orr+tid+128];
  float x2 = h3 ? hp[oh+tid+256] + res[orr+tid+256] : 0.f;
  float sum = blkReduceSum(x0+x1+x2, s_red);
  float m = sum/(float)GG;
  float d0=x0-m, d1=x1-m, d2=h3?(x2-m):0.f;
  float vs = blkReduceSum(d0*d0+d1*d1+d2*d2, s_red);
  float inv = 1.0f/sqrtf(vs/(float)GG + 1e-5f);
  float r0 = fmaxf(d0*inv*g[tid]     + bt[tid],     0.f);
  float r1 = fmaxf(d1*inv*g[tid+128] + bt[tid+128], 0.f);
  float r2 = h3 ? fmaxf(d2*inv*g[tid+256] + bt[tid+256], 0.f) : 0.f;
  if(f32out){
    size_t o = (size_t)row*f32_ld;
    f32out[o+tid] = r0; f32out[o+tid+128] = r1;
    if(h3) f32out[o+tid+256] = r2;
    else if(tid+256 < f32pad) f32out[o+tid+256] = 0.f;
  }
  if(bfout){
    size_t o = (size_t)row*bf_ld + bf_off;
    bfout[o+tid] = f2bf(r0); bfout[o+tid+128] = f2bf(r1);
    if(h3) bfout[o+tid+256] = f2bf(r2);
    else if(tid+256 < bfpad) bfout[o+tid+256] = 0;
  }
}

// ---------------------------------------------------------------------------
extern "C" void kernel_launch(void* const* d_in, const int* in_sizes, int n_in,
                              void* d_out, int out_size, void* d_ws, size_t ws_size,
                              hipStream_t stream){
  const float* h     = (const float*)d_in[0];
  const float* amask = (const float*)d_in[1];
  const float *syn0_W=(const float*)d_in[2], *syn0_a1=(const float*)d_in[3], *syn0_a2=(const float*)d_in[4],
              *syn0_pos=(const float*)d_in[5], *syn0_tW=(const float*)d_in[6], *syn0_tb=(const float*)d_in[7],
              *syn0_g=(const float*)d_in[8], *syn0_b=(const float*)d_in[9];
  const float *syn1_W=(const float*)d_in[10], *syn1_a1=(const float*)d_in[11], *syn1_a2=(const float*)d_in[12],
              *syn1_pos=(const float*)d_in[13], *syn1_g=(const float*)d_in[14], *syn1_b=(const float*)d_in[15];
  const float *sem0_W=(const float*)d_in[16], *sem0_a1=(const float*)d_in[17], *sem0_a2=(const float*)d_in[18],
              *sem0_pos=(const float*)d_in[19], *sem0_tW=(const float*)d_in[20], *sem0_tb=(const float*)d_in[21],
              *sem0_g=(const float*)d_in[22], *sem0_b=(const float*)d_in[23];
  const float *sem1_W=(const float*)d_in[24], *sem1_a1=(const float*)d_in[25], *sem1_a2=(const float*)d_in[26],
              *sem1_pos=(const float*)d_in[27], *sem1_g=(const float*)d_in[28], *sem1_b=(const float*)d_in[29];
  const float *fus_W=(const float*)d_in[30], *fus_b=(const float*)d_in[31];
  const int* synadj    = (const int*)d_in[32];
  const int* positions = (const int*)d_in[33];
  float* out = (float*)d_out;

  float* ws   = (float*)d_ws;
  float* vvec = ws;                  // 16384
  float* Svec = vvec + 16384;        // 64
  float* f1   = Svec + 64;           // 16384
  float* f2   = f1 + 16384;          // 16384
  float* Wh   = f2 + 16384;          // 16384*300 = 4,915,200
  float* T1   = Wh + 4915200;        // residual (stride 300)
  float* X1   = T1 + 4915200;        // LN0 out, stride 320 (zero-padded)
  float* T2   = X1 + 5242880;        // hp (stride 300)
  short* Xf      = (short*)(T2 + 4915200);  // fusion input [16384][608] bf16
  short* Wt_syn0 = Xf + 9961472;     // [640][768]
  short* Wt_sem0 = Wt_syn0 + 491520; // [640][768]
  short* Wt_syn1 = Wt_sem0 + 491520; // [320][320]
  short* Wt_sem1 = Wt_syn1 + 102400; // [320][320]
  short* Wt_fus  = Wt_sem1 + 102400; // [320][608]
  // total ~102.8 MB

  dim3 gAttn(BB, NN/8);
  dim3 gG2(256, 2), gG1(256, 1);
  int gF  = BB*NN/4;   // 4096
  int gLN = BB*NN;     // 16384

  k_semprep<<<BB,256,0,stream>>>(h, amask, vvec, Svec);

  k_wcast<<<1920,256,0,stream>>>(syn0_W, syn0_tW, Wt_syn0, 768, 768, 640, 320);
  k_wcast<<<1920,256,0,stream>>>(sem0_W, sem0_tW, Wt_sem0, 768, 768, 640, 320);
  k_wcast<<< 400,256,0,stream>>>(syn1_W, nullptr, Wt_syn1, 300, 320, 320, 0);
  k_wcast<<< 400,256,0,stream>>>(sem1_W, nullptr, Wt_sem1, 300, 320, 320, 0);
  k_wcast<<< 760,256,0,stream>>>(fus_W,  nullptr, Wt_fus,  600, 608, 320, 0);

  // syntactic layer 0
  k_gemm<768,1,float><<<gG2,256,0,stream>>>(h, Wt_syn0, syn0_pos, positions, syn0_tb, Wh, T1);
  k_f1f2<<<gF,256,0,stream>>>(Wh, syn0_a1, syn0_a2, f1, f2);
  k_attn<false><<<gAttn,256,0,stream>>>(Wh, f1, f2, synadj, nullptr, nullptr, T2);
  k_lnrelu<<<gLN,128,0,stream>>>(T2, T1, 300, syn0_g, syn0_b, X1, 320, 320, nullptr, 0, 0, 0);
  // syntactic layer 1 (identity residual)
  k_gemm<320,0,float><<<gG1,256,0,stream>>>(X1, Wt_syn1, syn1_pos, positions, nullptr, Wh, nullptr);
  k_f1f2<<<gF,256,0,stream>>>(Wh, syn1_a1, syn1_a2, f1, f2);
  k_attn<false><<<gAttn,256,0,stream>>>(Wh, f1, f2, synadj, nullptr, nullptr, T2);
  k_lnrelu<<<gLN,128,0,stream>>>(T2, X1, 320, syn1_g, syn1_b, nullptr, 0, 0, Xf, 608, 0, 300);

  // semantic layer 0
  k_gemm<768,1,float><<<gG2,256,0,stream>>>(h, Wt_sem0, sem0_pos, positions, sem0_tb, Wh, T1);
  k_f1f2<<<gF,256,0,stream>>>(Wh, sem0_a1, sem0_a2, f1, f2);
  k_attn<true><<<gAttn,256,0,stream>>>(Wh, f1, f2, nullptr, vvec, Svec, T2);
  k_lnrelu<<<gLN,128,0,stream>>>(T2, T1, 300, sem0_g, sem0_b, X1, 320, 320, nullptr, 0, 0, 0);
  // semantic layer 1
  k_gemm<320,0,float><<<gG1,256,0,stream>>>(X1, Wt_sem1, sem1_pos, positions, nullptr, Wh, nullptr);
  k_f1f2<<<gF,256,0,stream>>>(Wh, sem1_a1, sem1_a2, f1, f2);
  k_attn<true><<<gAttn,256,0,stream>>>(Wh, f1, f2, nullptr, vvec, Svec, T2);
  k_lnrelu<<<gLN,128,0,stream>>>(T2, X1, 320, sem1_g, sem1_b, nullptr, 0, 0, Xf, 608, 300, 308);

  // fusion: out = relu(concat @ fus_W + fus_b)
  k_gemm<608,2,short><<<gG1,256,0,stream>>>(Xf, Wt_fus, nullptr, nullptr, fus_b, out, nullptr);
}

// Round 6
// 892.627 us; speedup vs baseline: 1.9382x; 1.1449x over previous
//
#include <hip/hip_runtime.h>
#include <hip/hip_bf16.h>
#include <math.h>

#define BB 64
#define NN 256
#define DD 768
#define GG 300
#define KK 10
#define NEGV -9e15f

typedef __attribute__((ext_vector_type(8)))  short short8;
typedef __attribute__((ext_vector_type(4)))  short short4v;
typedef __attribute__((ext_vector_type(16))) float f32x16;

static __device__ __forceinline__ short f2bf(float f){
  __hip_bfloat16 b = __float2bfloat16(f);
  return __builtin_bit_cast(short, b);
}

// block reduction (blockDim multiple of 64, <=256). s must have >=4 floats.
__device__ __forceinline__ float blkReduceSum(float v, float* s){
  for(int o=32;o>0;o>>=1) v += __shfl_down(v,o,64);
  int nw = blockDim.x>>6;
  __syncthreads();
  if((threadIdx.x&63)==0) s[threadIdx.x>>6]=v;
  __syncthreads();
  float r=s[0];
  for(int i=1;i<nw;i++) r+=s[i];
  return r;
}

// ---------------------------------------------------------------------------
// Semantic prep stage A: arep[b][d] = masked mean of h over nodes.
// grid (64, 3): block = (batch, 256-dim chunk). Coalesced across threads.
// ---------------------------------------------------------------------------
__global__ __launch_bounds__(256) void k_arep(const float* __restrict__ h,
    const float* __restrict__ amask, float* __restrict__ arep){
  int b = blockIdx.x, tid = threadIdx.x;
  int d = blockIdx.y*256 + tid;
  __shared__ float s_mask[NN];
  __shared__ float s_red[4];
  s_mask[tid] = amask[b*NN+tid];
  float cnt = blkReduceSum(s_mask[tid], s_red);   // barrier inside covers s_mask
  const float* hb = h + (size_t)b*NN*DD + d;
  float a = 0.f;
  #pragma unroll 8
  for(int n=0;n<NN;n++) a += hb[(size_t)n*DD] * s_mask[n];
  arep[b*DD + d] = a/(cnt+1e-8f);
}

// ---------------------------------------------------------------------------
// Semantic prep stage B: sim[b][n] = cos(h[b,n,:], arep[b,:]).
// grid (64, 64): block = (batch, 4 nodes); one wave per node, float4 loads.
// ---------------------------------------------------------------------------
__global__ __launch_bounds__(256) void k_sim(const float* __restrict__ h,
    const float* __restrict__ arep, float* __restrict__ sim){
  int b = blockIdx.x, tid = threadIdx.x;
  int lane = tid&63, w = tid>>6;
  __shared__ __align__(16) float s_a[DD];
  __shared__ float s_red[4];
  float pa = 0.f;
  for(int d=tid; d<DD; d+=256){ float v = arep[b*DD+d]; s_a[d]=v; pa += v*v; }
  float na = blkReduceSum(pa, s_red);
  float nac = fmaxf(sqrtf(na), 1e-12f);
  int node = blockIdx.y*4 + w;
  const float* hr = h + ((size_t)b*NN+node)*DD;
  float dot=0.f, nn=0.f;
  #pragma unroll
  for(int q=0;q<3;q++){
    int c = lane*4 + q*256;
    float4 hv = *(const float4*)(hr + c);
    float4 av = *(const float4*)(s_a + c);
    dot += hv.x*av.x + hv.y*av.y + hv.z*av.z + hv.w*av.w;
    nn  += hv.x*hv.x + hv.y*hv.y + hv.z*hv.z + hv.w*hv.w;
  }
  for(int o=32;o>0;o>>=1){ dot += __shfl_down(dot,o,64); nn += __shfl_down(nn,o,64); }
  if(lane==0){
    nn = fmaxf(sqrtf(nn), 1e-12f);
    sim[b*NN+node] = dot/(nn*nac);
  }
}

// ---------------------------------------------------------------------------
// Semantic prep stage C: top-K per batch (stable = lowest-index tie-break).
// Emits scattered v[b,:] and S[b]; adjacency reconstructed in closed form.
// ---------------------------------------------------------------------------
__global__ __launch_bounds__(256) void k_topk(const float* __restrict__ sim,
    float* __restrict__ vout, float* __restrict__ Sout){
  int b = blockIdx.x, tid = threadIdx.x;
  __shared__ float s_bv[4]; __shared__ int s_bi[4];
  __shared__ float s_tv[KK]; __shared__ int s_ti[KK];
  __shared__ float s_v[NN];
  float v = sim[b*NN+tid];
  int lane = tid&63, w = tid>>6;
  for(int k=0;k<KK;k++){
    float bv = v; int bi_ = tid;
    for(int o=32;o>0;o>>=1){
      float ov = __shfl_down(bv,o,64); int oi = __shfl_down(bi_,o,64);
      if(ov>bv || (ov==bv && oi<bi_)){ bv=ov; bi_=oi; }
    }
    if(lane==0){ s_bv[w]=bv; s_bi[w]=bi_; }
    __syncthreads();
    float gb = s_bv[0]; int gi = s_bi[0];
    for(int i=1;i<4;i++){ if(s_bv[i]>gb || (s_bv[i]==gb && s_bi[i]<gi)){ gb=s_bv[i]; gi=s_bi[i]; } }
    if(tid==0){ s_tv[k]=gb; s_ti[k]=gi; }
    if(tid==gi) v = -1e30f;
    __syncthreads();
  }
  s_v[tid]=0.f;
  __syncthreads();
  if(tid<KK) s_v[s_ti[tid]] = s_tv[tid];
  __syncthreads();
  float S=0.f;
  for(int k=0;k<KK;k++) S += s_tv[k];
  vout[b*NN+tid] = s_v[tid];
  if(tid==0) Sout[b] = S;
}

// ---------------------------------------------------------------------------
// Weight cast+transpose+pad: dst[n][k] (bf16, [NPAD][KPAD]) from W[k][300].
// ---------------------------------------------------------------------------
__global__ __launch_bounds__(256) void k_wcast(const float* __restrict__ W1,
    const float* __restrict__ W2, short* __restrict__ dst,
    int K, int KPAD, int NPAD, int n2off){
  int idx = blockIdx.x*256 + threadIdx.x;
  if(idx >= NPAD*KPAD) return;
  int n = idx / KPAD, k = idx % KPAD;
  float v = 0.f;
  if(k < K){
    if(n < 300) v = W1[(size_t)k*300 + n];
    else if(W2 && n >= n2off && n < n2off+300) v = W2[(size_t)k*300 + (n - n2off)];
  }
  dst[idx] = f2bf(v);
}

// ---------------------------------------------------------------------------
// MFMA GEMM: Y = X @ Wt^T, Wt[NPAD][KPAD] bf16 (pre-transposed).
// BM=64, BN=320, BK=32; mfma_f32_32x32x16_bf16, verified layouts.
// MODE 0: Y1 = acc + posemb[positions[row]][n]
// MODE 1: + dual half: Y2 = acc + tvec[n-320]
// MODE 2: Y1 = relu(acc + tvec[n])   (fusion -> d_out)
// ---------------------------------------------------------------------------
template<int KPAD, int MODE, typename XT>
__global__ __launch_bounds__(256) void k_gemm(const XT* __restrict__ X,
    const short* __restrict__ Bt, const float* __restrict__ posemb,
    const int* __restrict__ positions, const float* __restrict__ tvec,
    float* __restrict__ Y1, float* __restrict__ Y2){
  __shared__ __align__(16) short sX[64*40];
  __shared__ __align__(16) short sB[320*40];
  const int tid = threadIdx.x;
  const int lane = tid & 63, wave = tid >> 6;
  const int rgrp = wave & 1, cgrp = wave >> 1;
  const int row0 = blockIdx.x * 64;
  const int ncol0 = blockIdx.y * 320;
  const int lo = lane & 31, hi = lane >> 5;

  f32x16 acc[5];
  #pragma unroll
  for(int t=0;t<5;t++)
    #pragma unroll
    for(int i=0;i<16;i++) acc[t][i] = 0.f;

  for(int k0=0; k0<KPAD; k0+=32){
    __syncthreads();
    if constexpr (sizeof(XT)==4){
      #pragma unroll
      for(int c=tid; c<512; c+=256){
        int r=c>>3, cc=c&7;
        float4 v = *(const float4*)(X + (size_t)(row0+r)*KPAD + k0 + cc*4);
        short4v s; s.x=f2bf(v.x); s.y=f2bf(v.y); s.z=f2bf(v.z); s.w=f2bf(v.w);
        *(short4v*)(sX + r*40 + cc*4) = s;
      }
    } else {
      if(tid < 256){
        int r=tid>>2, cc=tid&3;
        *(short8*)(sX + r*40 + cc*8) = *(const short8*)(X + (size_t)(row0+r)*KPAD + k0 + cc*8);
      }
    }
    #pragma unroll
    for(int c=tid; c<1280; c+=256){
      int r=c>>2, cc=c&3;
      *(short8*)(sB + r*40 + cc*8) = *(const short8*)(Bt + (size_t)(ncol0+r)*KPAD + k0 + cc*8);
    }
    __syncthreads();
    #pragma unroll
    for(int ss=0; ss<2; ss++){
      int kb = ss*16 + hi*8;
      short8 a = *(const short8*)(sX + (rgrp*32 + lo)*40 + kb);
      #pragma unroll
      for(int t=0;t<5;t++){
        short8 b = *(const short8*)(sB + (cgrp*160 + t*32 + lo)*40 + kb);
        acc[t] = __builtin_amdgcn_mfma_f32_32x32x16_bf16(a, b, acc[t], 0, 0, 0);
      }
    }
  }

  #pragma unroll
  for(int r=0;r<16;r++){
    int row = row0 + rgrp*32 + (r&3) + 8*(r>>2) + 4*hi;
    int p = 0;
    if(MODE!=2) p = positions[row];
    #pragma unroll
    for(int t=0;t<5;t++){
      int nc = ncol0 + cgrp*160 + t*32 + lo;
      float v = acc[t][r];
      if(MODE==2){
        if(nc < 300) Y1[(size_t)row*300 + nc] = fmaxf(v + tvec[nc], 0.f);
      } else {
        if(nc < 300) Y1[(size_t)row*300 + nc] = v + posemb[(size_t)p*300 + nc];
        else if(MODE==1 && nc>=320 && nc<620) Y2[(size_t)row*300 + (nc-320)] = v + tvec[nc-320];
      }
    }
  }
}

// ---------------------------------------------------------------------------
// f1/f2: one wave per row
// ---------------------------------------------------------------------------
__global__ __launch_bounds__(256) void k_f1f2(const float* __restrict__ Wh,
    const float* __restrict__ a1, const float* __restrict__ a2,
    float* __restrict__ f1, float* __restrict__ f2){
  int row = blockIdx.x*4 + (threadIdx.x>>6);
  int lane = threadIdx.x&63;
  const float* wr = Wh + (size_t)row*GG;
  float s1=0.f, s2=0.f;
  for(int c=lane;c<GG;c+=64){ float wv=wr[c]; s1 += wv*a1[c]; s2 += wv*a2[c]; }
  for(int o=32;o>0;o>>=1){ s1+=__shfl_down(s1,o,64); s2+=__shfl_down(s2,o,64); }
  if(lane==0){ f1[row]=s1; f2[row]=s2; }
}

// ---------------------------------------------------------------------------
// Fused attention + residual + LayerNorm + ReLU.
// Block = (batch, 8 rows), 256 thr. Softmax: wave-per-row.
// NOTE (round-5 bug fix): res/f32out/bfout are indexed by GLOBAL row
// b*NN + i0 + r, not the within-batch row. Round 5 omitted b*NN -> 63/64 of
// Xf/X1 rows stayed poisoned -> all-zero output after relu.
// ---------------------------------------------------------------------------
template<bool SEM>
__global__ __launch_bounds__(256) void k_attn_ln(const float* __restrict__ Wh,
    const float* __restrict__ f1, const float* __restrict__ f2,
    const int* __restrict__ adjI, const float* __restrict__ vvec,
    const float* __restrict__ Svec,
    const float* __restrict__ res, int res_ld,
    const float* __restrict__ g, const float* __restrict__ bt,
    float* __restrict__ f32out, int f32_ld, int f32pad,
    short* __restrict__ bfout, int bf_ld, int bf_off, int bfpad){
  int b = blockIdx.x, i0 = blockIdx.y*8, tid = threadIdx.x;
  int lane = tid&63, w = tid>>6;
  __shared__ float s_f2[NN];
  __shared__ float s_v[NN];
  __shared__ __align__(16) float s_p[8][NN];
  __shared__ float s_hp[8][304];
  s_f2[tid] = f2[b*NN+tid];
  float S = 0.f;
  if(SEM){ s_v[tid] = vvec[b*NN+tid]; S = Svec[b]; }
  __syncthreads();

  // ---- softmax: wave w handles rows w and w+4 ----
  #pragma unroll
  for(int rr=0; rr<2; rr++){
    int r = w + rr*4;
    int i = i0 + r;
    float fi = f1[b*NN+i];
    float vi = SEM ? s_v[i] : 0.f;
    float denom = 0.f;
    if(SEM) denom = 0.5f*((float)NN*vi + S) + 1.f + 1e-8f;
    float e[4]; float mx = -INFINITY;
    #pragma unroll
    for(int q=0;q<4;q++){
      int j = lane + q*64;
      float ee = fi + s_f2[j];
      ee = ee>0.f ? ee : 0.2f*ee;
      bool m;
      if(SEM){
        float val = 0.5f*(vi + s_v[j]) + (i==j ? 1.f : 0.f);
        m = (denom > 0.f) ? (val > 0.f) : (val < 0.f);
      } else {
        m = adjI[((size_t)b*NN+i)*NN + j] > 0;
      }
      ee = m ? ee : NEGV;
      e[q] = ee; mx = fmaxf(mx, ee);
    }
    for(int o=32;o>0;o>>=1) mx = fmaxf(mx, __shfl_xor(mx,o,64));
    float sm = 0.f;
    #pragma unroll
    for(int q=0;q<4;q++){ e[q] = expf(e[q]-mx); sm += e[q]; }
    for(int o=32;o>0;o>>=1) sm += __shfl_xor(sm,o,64);
    float inv = 1.f/sm;
    #pragma unroll
    for(int q=0;q<4;q++) s_p[r][lane+q*64] = e[q]*inv;
  }
  __syncthreads();

  // ---- aggregation: hp = P @ Wh (fp32 VALU) ----
  bool has2 = tid < (GG-256);   // 44
  float aa[8]={0,0,0,0,0,0,0,0}, ab[8]={0,0,0,0,0,0,0,0};
  const float* whb = Wh + (size_t)b*NN*GG;
  for(int j4=0; j4<NN; j4+=4){
    float4 pj[8];
    #pragma unroll
    for(int r=0;r<8;r++) pj[r] = *(const float4*)&s_p[r][j4];
    #pragma unroll
    for(int q=0;q<4;q++){
      int j = j4+q;
      float wa = whb[(size_t)j*GG+tid];
      float wb = has2 ? whb[(size_t)j*GG+tid+256] : 0.f;
      #pragma unroll
      for(int r=0;r<8;r++){
        float p = (q==0)?pj[r].x : (q==1)?pj[r].y : (q==2)?pj[r].z : pj[r].w;
        aa[r]=fmaf(p,wa,aa[r]); ab[r]=fmaf(p,wb,ab[r]);
      }
    }
  }

  // ---- add residual (GLOBAL row), park in LDS for row-wise LN ----
  #pragma unroll
  for(int r=0;r<8;r++){
    int row = b*NN + i0 + r;
    s_hp[r][tid] = aa[r] + res[(size_t)row*res_ld + tid];
    if(has2) s_hp[r][tid+256] = ab[r] + res[(size_t)row*res_ld + tid+256];
  }
  __syncthreads();

  // ---- LayerNorm + ReLU: wave w handles rows w and w+4 ----
  #pragma unroll
  for(int rr=0; rr<2; rr++){
    int r = w + rr*4;
    int row = b*NN + i0 + r;
    float x[5]; float sum = 0.f;
    #pragma unroll
    for(int q=0;q<5;q++){
      int c = lane + q*64;
      float xv = (c<GG) ? s_hp[r][c] : 0.f;
      x[q]=xv; sum += xv;
    }
    for(int o=32;o>0;o>>=1) sum += __shfl_xor(sum,o,64);
    float m = sum/(float)GG;
    float sq = 0.f;
    #pragma unroll
    for(int q=0;q<5;q++){
      int c = lane + q*64;
      float d = (c<GG) ? (x[q]-m) : 0.f;
      x[q]=d; sq += d*d;
    }
    for(int o=32;o>0;o>>=1) sq += __shfl_xor(sq,o,64);
    float inv = 1.0f/sqrtf(sq/(float)GG + 1e-5f);
    #pragma unroll
    for(int q=0;q<5;q++){
      int c = lane + q*64;
      if(c<GG){
        float yv = fmaxf(x[q]*inv*g[c] + bt[c], 0.f);
        if(f32out) f32out[(size_t)row*f32_ld + c] = yv;
        if(bfout)  bfout[(size_t)row*bf_ld + bf_off + c] = f2bf(yv);
      } else {
        if(f32out && c < f32pad) f32out[(size_t)row*f32_ld + c] = 0.f;
        if(bfout  && c < bfpad)  bfout[(size_t)row*bf_ld + bf_off + c] = 0;
      }
    }
  }
}

// ---------------------------------------------------------------------------
extern "C" void kernel_launch(void* const* d_in, const int* in_sizes, int n_in,
                              void* d_out, int out_size, void* d_ws, size_t ws_size,
                              hipStream_t stream){
  const float* h     = (const float*)d_in[0];
  const float* amask = (const float*)d_in[1];
  const float *syn0_W=(const float*)d_in[2], *syn0_a1=(const float*)d_in[3], *syn0_a2=(const float*)d_in[4],
              *syn0_pos=(const float*)d_in[5], *syn0_tW=(const float*)d_in[6], *syn0_tb=(const float*)d_in[7],
              *syn0_g=(const float*)d_in[8], *syn0_b=(const float*)d_in[9];
  const float *syn1_W=(const float*)d_in[10], *syn1_a1=(const float*)d_in[11], *syn1_a2=(const float*)d_in[12],
              *syn1_pos=(const float*)d_in[13], *syn1_g=(const float*)d_in[14], *syn1_b=(const float*)d_in[15];
  const float *sem0_W=(const float*)d_in[16], *sem0_a1=(const float*)d_in[17], *sem0_a2=(const float*)d_in[18],
              *sem0_pos=(const float*)d_in[19], *sem0_tW=(const float*)d_in[20], *sem0_tb=(const float*)d_in[21],
              *sem0_g=(const float*)d_in[22], *sem0_b=(const float*)d_in[23];
  const float *sem1_W=(const float*)d_in[24], *sem1_a1=(const float*)d_in[25], *sem1_a2=(const float*)d_in[26],
              *sem1_pos=(const float*)d_in[27], *sem1_g=(const float*)d_in[28], *sem1_b=(const float*)d_in[29];
  const float *fus_W=(const float*)d_in[30], *fus_b=(const float*)d_in[31];
  const int* synadj    = (const int*)d_in[32];
  const int* positions = (const int*)d_in[33];
  float* out = (float*)d_out;

  float* ws   = (float*)d_ws;
  float* vvec = ws;                  // 16384
  float* Svec = vvec + 16384;        // 64
  float* f1   = Svec + 64;           // 16384
  float* f2   = f1 + 16384;          // 16384
  float* arep = f2 + 16384;          // 64*768 = 49152
  float* simb = arep + 49152;        // 16384
  float* Wh   = simb + 16384;        // 4,915,200
  float* T1   = Wh + 4915200;        // residual (stride 300)
  float* X1   = T1 + 4915200;        // LN0 out, stride 320 (zero-padded)
  short* Xf      = (short*)(X1 + 5242880);  // fusion input [16384][608] bf16
  short* Wt_syn0 = Xf + 9961472;     // [640][768]
  short* Wt_sem0 = Wt_syn0 + 491520; // [640][768]
  short* Wt_syn1 = Wt_sem0 + 491520; // [320][320]
  short* Wt_sem1 = Wt_syn1 + 102400; // [320][320]
  short* Wt_fus  = Wt_sem1 + 102400; // [320][608]

  dim3 gAttn(BB, NN/8);
  dim3 gG2(256, 2), gG1(256, 1);
  int gF = BB*NN/4;   // 4096

  // semantic prep (parallel, coalesced)
  k_arep<<<dim3(BB,3),256,0,stream>>>(h, amask, arep);
  k_sim <<<dim3(BB,64),256,0,stream>>>(h, arep, simb);
  k_topk<<<BB,256,0,stream>>>(simb, vvec, Svec);

  k_wcast<<<1920,256,0,stream>>>(syn0_W, syn0_tW, Wt_syn0, 768, 768, 640, 320);
  k_wcast<<<1920,256,0,stream>>>(sem0_W, sem0_tW, Wt_sem0, 768, 768, 640, 320);
  k_wcast<<< 400,256,0,stream>>>(syn1_W, nullptr, Wt_syn1, 300, 320, 320, 0);
  k_wcast<<< 400,256,0,stream>>>(sem1_W, nullptr, Wt_sem1, 300, 320, 320, 0);
  k_wcast<<< 760,256,0,stream>>>(fus_W,  nullptr, Wt_fus,  600, 608, 320, 0);

  // syntactic layer 0
  k_gemm<768,1,float><<<gG2,256,0,stream>>>(h, Wt_syn0, syn0_pos, positions, syn0_tb, Wh, T1);
  k_f1f2<<<gF,256,0,stream>>>(Wh, syn0_a1, syn0_a2, f1, f2);
  k_attn_ln<false><<<gAttn,256,0,stream>>>(Wh, f1, f2, synadj, nullptr, nullptr,
      T1, 300, syn0_g, syn0_b, X1, 320, 320, nullptr, 0, 0, 0);
  // syntactic layer 1 (identity residual) -> Xf cols [0,300)
  k_gemm<320,0,float><<<gG1,256,0,stream>>>(X1, Wt_syn1, syn1_pos, positions, nullptr, Wh, nullptr);
  k_f1f2<<<gF,256,0,stream>>>(Wh, syn1_a1, syn1_a2, f1, f2);
  k_attn_ln<false><<<gAttn,256,0,stream>>>(Wh, f1, f2, synadj, nullptr, nullptr,
      X1, 320, syn1_g, syn1_b, nullptr, 0, 0, Xf, 608, 0, 300);

  // semantic layer 0
  k_gemm<768,1,float><<<gG2,256,0,stream>>>(h, Wt_sem0, sem0_pos, positions, sem0_tb, Wh, T1);
  k_f1f2<<<gF,256,0,stream>>>(Wh, sem0_a1, sem0_a2, f1, f2);
  k_attn_ln<true><<<gAttn,256,0,stream>>>(Wh, f1, f2, nullptr, vvec, Svec,
      T1, 300, sem0_g, sem0_b, X1, 320, 320, nullptr, 0, 0, 0);
  // semantic layer 1 -> Xf cols [300,600), zero-pad [600,608)
  k_gemm<320,0,float><<<gG1,256,0,stream>>>(X1, Wt_sem1, sem1_pos, positions, nullptr, Wh, nullptr);
  k_f1f2<<<gF,256,0,stream>>>(Wh, sem1_a1, sem1_a2, f1, f2);
  k_attn_ln<true><<<gAttn,256,0,stream>>>(Wh, f1, f2, nullptr, vvec, Svec,
      X1, 320, sem1_g, sem1_b, nullptr, 0, 0, Xf, 608, 300, 308);

  // fusion: out = relu(concat @ fus_W + fus_b)
  k_gemm<608,2,short><<<gG1,256,0,stream>>>(Xf, Wt_fus, nullptr, nullptr, fus_b, out, nullptr);
}